// Round 6
// baseline (1266.687 us; speedup 1.0000x reference)
//
#include <hip/hip_runtime.h>
#include <stdint.h>

typedef __attribute__((ext_vector_type(8))) short bf16x8;   // 8 bf16 = 4 VGPRs
typedef __attribute__((ext_vector_type(4))) float f32x4;

__device__ __forceinline__ float bf2f(unsigned short b) {
    union { unsigned u; float f; } c; c.u = ((unsigned)b) << 16; return c.f;
}
__device__ __forceinline__ unsigned short f2bf(float f) {
    union { float f; unsigned u; } c; c.f = f;
    unsigned u = c.u;
    u += 0x7fffu + ((u >> 16) & 1u);          // round-to-nearest-even
    return (unsigned short)(u >> 16);
}

__global__ void GNNEncoder_317827579954_kernel() {}

__global__ void k_zero(int* __restrict__ p, int n) {
    int i = blockIdx.x * 256 + threadIdx.x;
    if (i < n) p[i] = 0;
}

// flags[0] = 1 if dense inputs are f32 (else bf16); flags[1] = 1 if edge_index is int64.
__global__ void k_flags(const unsigned* __restrict__ x, const int* __restrict__ ei,
                        int E, int* __restrict__ flags) {
    if (threadIdx.x != 0 || blockIdx.x != 0) return;
    int plausible = 0;
    for (int i = 0; i < 256; ++i) {
        unsigned u = x[i] & 0xffffu;
        unsigned e = (u >> 7) & 0xffu;
        if ((e >= 100u && e <= 145u) || u == 0u) ++plausible;
    }
    flags[0] = (plausible >= 192) ? 0 : 1;
    int n = E < 128 ? E : 128;
    int is64 = 1;
    for (int i = 0; i < n; ++i) {
        if (ei[2 * i + 1] != 0) { is64 = 0; break; }
    }
    flags[1] = is64;
}

// Normalize x into bf16, 8 elements/thread (vectorized copy on bf16 path).
__global__ void k_cvt8(const void* __restrict__ in, unsigned short* __restrict__ out,
                       int n8, const int* __restrict__ flags) {
    int i = blockIdx.x * 256 + threadIdx.x;
    if (i >= n8) return;
    if (flags[0]) {
        const float4* f = (const float4*)in;
        float4 x0 = f[i * 2], x1 = f[i * 2 + 1];
        union { unsigned short s[8]; uint4 v; } o;
        o.s[0] = f2bf(x0.x); o.s[1] = f2bf(x0.y); o.s[2] = f2bf(x0.z); o.s[3] = f2bf(x0.w);
        o.s[4] = f2bf(x1.x); o.s[5] = f2bf(x1.y); o.s[6] = f2bf(x1.z); o.s[7] = f2bf(x1.w);
        ((uint4*)out)[i] = o.v;
    } else {
        ((uint4*)out)[i] = ((const uint4*)in)[i];
    }
}

// W [k][n] (raw dtype) -> Wt [n][k] bf16 (256x256)
__global__ void k_cvtT(const void* __restrict__ W, unsigned short* __restrict__ Wt,
                       const int* __restrict__ flags) {
    int n = blockIdx.x, k = threadIdx.x;
    unsigned short v;
    if (flags[0]) v = f2bf(((const float*)W)[k * 256 + n]);
    else          v = ((const unsigned short*)W)[k * 256 + n];
    Wt[n * 256 + k] = v;
}

// deg[v] = #(dst == v)
__global__ void k_count(const int* __restrict__ ei, int E, const int* __restrict__ flags,
                        int* __restrict__ deg) {
    int i = blockIdx.x * blockDim.x + threadIdx.x;
    if (i >= E) return;
    int d = flags[1] ? ei[2 * E + 2 * i] : ei[E + i];
    atomicAdd(&deg[d], 1);
}

// single-block exclusive scan -> offs, cursor, dinv = rsqrt(deg+1)
__global__ void k_scan(const int* __restrict__ deg, int* __restrict__ offs,
                       int* __restrict__ cursor, float* __restrict__ dinv, int N) {
    __shared__ int sums[256];
    __shared__ int pref[257];
    int t = threadIdx.x;
    int chunk = (N + 255) / 256;
    int lo = t * chunk;
    int hi = lo + chunk; if (hi > N) hi = N;
    int s = 0;
    for (int i = lo; i < hi; ++i) s += deg[i];
    sums[t] = s;
    __syncthreads();
    if (t == 0) {
        int run = 0;
        for (int i = 0; i < 256; ++i) { pref[i] = run; run += sums[i]; }
        pref[256] = run;
    }
    __syncthreads();
    int run = pref[t];
    for (int i = lo; i < hi; ++i) {
        offs[i] = run; cursor[i] = run;
        run += deg[i];
        dinv[i] = rsqrtf((float)(deg[i] + 1));   // +1 = self loop
    }
    if (t == 0) offs[N] = pref[256];
}

// counting-sort CSR fill: csr[slot(dst)] = src
__global__ void k_fill(const int* __restrict__ ei, int E, const int* __restrict__ flags,
                       int* __restrict__ cursor, int* __restrict__ csr) {
    int i = blockIdx.x * blockDim.x + threadIdx.x;
    if (i >= E) return;
    int s, d;
    if (flags[1]) { s = ei[2 * i];     d = ei[2 * E + 2 * i]; }
    else          { s = ei[i];         d = ei[E + i]; }
    int p = atomicAdd(&cursor[d], 1);
    csr[p] = s;
}

// C[M,256] = A[M,256] @ Bt^T. 1D grid; wave computes 16 rows x 256 cols.
// A is read exactly once; Bt (128 KB) re-read from L2.
__global__ __launch_bounds__(256) void k_gemm(const unsigned short* __restrict__ A,
                                              const unsigned short* __restrict__ Bt,
                                              unsigned short* __restrict__ C, int M) {
    int tid  = threadIdx.x;
    int lane = tid & 63;
    int wave = tid >> 6;
    int q = lane >> 4;                 // quad 0..3
    int r = lane & 15;
    int rowBase = blockIdx.x * 64 + wave * 16;

    int arow = rowBase + r;
    arow = arow < M ? arow : M - 1;    // clamp; discarded on store
    const unsigned short* aptr = A + (size_t)arow * 256;

    f32x4 acc[16] = {};
    for (int kk = 0; kk < 256; kk += 32) {
        int k = kk + q * 8;            // frag: [m|n = lane&15][k = quad*8 + j]
        bf16x8 a = *(const bf16x8*)(aptr + k);
#pragma unroll
        for (int nt = 0; nt < 16; ++nt) {
            bf16x8 b = *(const bf16x8*)(Bt + (size_t)(nt * 16 + r) * 256 + k);
            acc[nt] = __builtin_amdgcn_mfma_f32_16x16x32_bf16(a, b, acc[nt], 0, 0, 0);
        }
    }
#pragma unroll
    for (int nt = 0; nt < 16; ++nt) {
        int col = nt * 16 + r;
#pragma unroll
        for (int r2 = 0; r2 < 4; ++r2) {
            int row = rowBase + q * 4 + r2;    // C/D: col=lane&15, row=q*4+reg
            if (row < M) C[(size_t)row * 256 + col] = f2bf(acc[nt][r2]);
        }
    }
}

// Channel-blocked aggregation: grid (ceil(N/4), 8). Chunk = 32 channels (3.2 MB
// gather working set -> L2-resident). Wave = 4 edge-slots x 16 lanes (2 ch/lane).
__global__ __launch_bounds__(256) void k_agg(const unsigned short* __restrict__ XW,
                                             const int* __restrict__ csr,
                                             const int* __restrict__ offs,
                                             const float* __restrict__ dinv,
                                             const void* __restrict__ bias,
                                             void* __restrict__ out,
                                             int relu, int final_, const int* __restrict__ flags,
                                             int N) {
    int v = blockIdx.x * 4 + (threadIdx.x >> 6);
    if (v >= N) return;
    int lane = threadIdx.x & 63;
    int g = lane >> 4;                 // edge slot 0..3
    int r = lane & 15;                 // channel pair within chunk
    int c = blockIdx.y * 32 + r * 2;   // absolute channel
    float a0 = 0.f, a1 = 0.f;
    int beg = offs[v], end = offs[v + 1];
    for (int e = beg + g; e < end; e += 4) {
        int s = csr[e];
        float w = dinv[s];
        unsigned u = *(const unsigned*)(XW + (size_t)s * 256 + c);
        a0 += w * bf2f((unsigned short)(u & 0xffffu));
        a1 += w * bf2f((unsigned short)(u >> 16));
    }
    a0 += __shfl_xor(a0, 16); a1 += __shfl_xor(a1, 16);
    a0 += __shfl_xor(a0, 32); a1 += __shfl_xor(a1, 32);
    if (g == 0) {
        float dv = dinv[v];
        float dv2 = dv * dv;
        unsigned su = *(const unsigned*)(XW + (size_t)v * 256 + c);
        float b0, b1;
        if (flags[0]) {
            b0 = ((const float*)bias)[c]; b1 = ((const float*)bias)[c + 1];
        } else {
            b0 = bf2f(((const unsigned short*)bias)[c]);
            b1 = bf2f(((const unsigned short*)bias)[c + 1]);
        }
        float r0 = dv * a0 + dv2 * bf2f((unsigned short)(su & 0xffffu)) + b0;
        float r1 = dv * a1 + dv2 * bf2f((unsigned short)(su >> 16))     + b1;
        if (relu) { r0 = fmaxf(r0, 0.f); r1 = fmaxf(r1, 0.f); }
        if (final_ && flags[0]) {
            float2 o; o.x = r0; o.y = r1;
            *(float2*)((float*)out + (size_t)v * 256 + c) = o;
        } else {
            *(unsigned*)((unsigned short*)out + (size_t)v * 256 + c) =
                (unsigned)f2bf(r0) | ((unsigned)f2bf(r1) << 16);
        }
    }
}

extern "C" void kernel_launch(void* const* d_in, const int* in_sizes, int n_in,
                              void* d_out, int out_size, void* d_ws, size_t ws_size,
                              hipStream_t stream) {
    (void)n_in; (void)out_size; (void)ws_size;
    const void* x  = d_in[0];
    const int*  ei = (const int*)d_in[1];
    const void* W1 = d_in[2];
    const void* b1 = d_in[3];
    const void* W2 = d_in[4];
    const void* b2 = d_in[5];

    int N = in_sizes[0] / 256;          // 50000
    int E = in_sizes[1] / 2;            // 1600000

    char* p = (char*)d_ws;
    auto alloc = [&](size_t bytes) {
        char* r = p;
        p += (bytes + 255) & ~(size_t)255;
        return r;
    };
    int*            flags  = (int*)alloc(8);
    int*            deg    = (int*)alloc((size_t)N * 4);
    int*            cursor = (int*)alloc((size_t)N * 4);
    int*            offs   = (int*)alloc(((size_t)N + 1) * 4);
    float*          dinv   = (float*)alloc((size_t)N * 4);
    unsigned short* wt1    = (unsigned short*)alloc(256 * 256 * 2);
    unsigned short* wt2    = (unsigned short*)alloc(256 * 256 * 2);
    int*            csr    = (int*)alloc((size_t)E * 4);
    unsigned short* buf0   = (unsigned short*)alloc((size_t)N * 256 * 2);
    unsigned short* buf1   = (unsigned short*)alloc((size_t)N * 256 * 2);

    int nF = N * 256;
    int gE = (E + 255) / 256;

    k_flags<<<1, 64, 0, stream>>>((const unsigned*)x, ei, E, flags);
    k_zero<<<(N + 255) / 256, 256, 0, stream>>>(deg, N);
    k_count<<<gE, 256, 0, stream>>>(ei, E, flags, deg);
    k_scan<<<1, 256, 0, stream>>>(deg, offs, cursor, dinv, N);
    k_fill<<<gE, 256, 0, stream>>>(ei, E, flags, cursor, csr);

    k_cvt8<<<(nF / 8 + 255) / 256, 256, 0, stream>>>(x, buf0, nF / 8, flags);
    k_cvtT<<<256, 256, 0, stream>>>(W1, wt1, flags);
    k_cvtT<<<256, 256, 0, stream>>>(W2, wt2, flags);

    dim3 ga((N + 3) / 4, 8);
    k_gemm<<<(N + 63) / 64, 256, 0, stream>>>(buf0, wt1, buf1, N);           // XW1
    k_agg<<<ga, 256, 0, stream>>>(buf1, csr, offs, dinv, b1,
                                  (void*)buf0, 1, 0, flags, N);              // h (bf16)
    k_gemm<<<(N + 63) / 64, 256, 0, stream>>>(buf0, wt2, buf1, N);           // HW2
    k_agg<<<ga, 256, 0, stream>>>(buf1, csr, offs, dinv, b2,
                                  d_out, 0, 1, flags, N);                    // final
}

// Round 7
// 954.824 us; speedup vs baseline: 1.3266x; 1.3266x over previous
//
#include <hip/hip_runtime.h>
#include <stdint.h>

typedef __attribute__((ext_vector_type(8))) short bf16x8;   // 8 bf16 = 4 VGPRs
typedef __attribute__((ext_vector_type(4))) float f32x4;

__device__ __forceinline__ float bf2f(unsigned short b) {
    union { unsigned u; float f; } c; c.u = ((unsigned)b) << 16; return c.f;
}
__device__ __forceinline__ unsigned short f2bf(float f) {
    union { float f; unsigned u; } c; c.f = f;
    unsigned u = c.u;
    u += 0x7fffu + ((u >> 16) & 1u);          // round-to-nearest-even
    return (unsigned short)(u >> 16);
}

__global__ void GNNEncoder_317827579954_kernel() {}

__global__ void k_zero(int* __restrict__ p, int n) {
    int i = blockIdx.x * 256 + threadIdx.x;
    if (i < n) p[i] = 0;
}

// flags[0] = 1 if dense inputs are f32 (else bf16); flags[1] = 1 if edge_index is int64.
// One wave, parallel: 4 samples/lane + ballot.
__global__ void k_flags(const unsigned* __restrict__ x, const int* __restrict__ ei,
                        int E, int* __restrict__ flags) {
    int t = threadIdx.x;              // 0..63
    int pl = 0;
    for (int i = t; i < 256; i += 64) {
        unsigned u = x[i] & 0xffffu;
        unsigned e = (u >> 7) & 0xffu;
        if ((e >= 100u && e <= 145u) || u == 0u) ++pl;
    }
    for (int off = 32; off; off >>= 1) pl += __shfl_down(pl, off);
    int n = E < 64 ? E : 64;
    unsigned long long nz = __ballot(t < n ? (ei[2 * t + 1] != 0) : 0);
    if (t == 0) {
        flags[0] = (pl >= 192) ? 0 : 1;       // 0 = bf16, 1 = f32
        flags[1] = (nz == 0ull) ? 1 : 0;      // 1 = int64
    }
}

// Normalize x into bf16, 8 elements/thread.
__global__ void k_cvt8(const void* __restrict__ in, unsigned short* __restrict__ out,
                       int n8, const int* __restrict__ flags) {
    int i = blockIdx.x * 256 + threadIdx.x;
    if (i >= n8) return;
    if (flags[0]) {
        const float4* f = (const float4*)in;
        float4 x0 = f[i * 2], x1 = f[i * 2 + 1];
        union { unsigned short s[8]; uint4 v; } o;
        o.s[0] = f2bf(x0.x); o.s[1] = f2bf(x0.y); o.s[2] = f2bf(x0.z); o.s[3] = f2bf(x0.w);
        o.s[4] = f2bf(x1.x); o.s[5] = f2bf(x1.y); o.s[6] = f2bf(x1.z); o.s[7] = f2bf(x1.w);
        ((uint4*)out)[i] = o.v;
    } else {
        ((uint4*)out)[i] = ((const uint4*)in)[i];
    }
}

// W [k][n] (raw dtype) -> Wt [n][k] bf16 (256x256)
__global__ void k_cvtT(const void* __restrict__ W, unsigned short* __restrict__ Wt,
                       const int* __restrict__ flags) {
    int n = blockIdx.x, k = threadIdx.x;
    unsigned short v;
    if (flags[0]) v = f2bf(((const float*)W)[k * 256 + n]);
    else          v = ((const unsigned short*)W)[k * 256 + n];
    Wt[n * 256 + k] = v;
}

// deg[v] = #(dst == v)
__global__ void k_count(const int* __restrict__ ei, int E, const int* __restrict__ flags,
                        int* __restrict__ deg) {
    int i = blockIdx.x * blockDim.x + threadIdx.x;
    if (i >= E) return;
    int d = flags[1] ? ei[2 * E + 2 * i] : ei[E + i];
    atomicAdd(&deg[d], 1);
}

// ---- parallel exclusive scan over deg (3 kernels) ----
__global__ void k_bsum(const int* __restrict__ deg, int* __restrict__ bsum, int N) {
    __shared__ int sc[256];
    int t = threadIdx.x;
    int i = blockIdx.x * 256 + t;
    int d = i < N ? deg[i] : 0;
    sc[t] = d;
    __syncthreads();
    for (int off = 128; off; off >>= 1) {
        if (t < off) sc[t] += sc[t + off];
        __syncthreads();
    }
    if (t == 0) bsum[blockIdx.x] = sc[0];
}

__global__ void k_bscan(const int* __restrict__ bsum, int* __restrict__ bpref, int nb) {
    __shared__ int sc[1024];
    int t = threadIdx.x;
    if (t < nb) sc[t] = bsum[t];
    __syncthreads();
    if (t == 0) {
        int run = 0;
        for (int i = 0; i < nb; ++i) { int v = sc[i]; bpref[i] = run; run += v; }
    }
}

__global__ void k_offs(const int* __restrict__ deg, const int* __restrict__ bpref,
                       int* __restrict__ offs, int* __restrict__ cursor,
                       float* __restrict__ dinv, int N) {
    __shared__ int sc[256];
    int t = threadIdx.x;
    int i = blockIdx.x * 256 + t;
    int d = (i < N) ? deg[i] : 0;
    sc[t] = d;
    __syncthreads();
    for (int off = 1; off < 256; off <<= 1) {
        int v = (t >= off) ? sc[t - off] : 0;
        __syncthreads();
        sc[t] += v;
        __syncthreads();
    }
    if (i < N) {
        int ex = sc[t] - d + bpref[blockIdx.x];
        offs[i] = ex; cursor[i] = ex;
        dinv[i] = rsqrtf((float)(d + 1));     // +1 = self loop
        if (i == N - 1) offs[N] = ex + d;
    }
}

// counting-sort CSR fill: csr[slot(dst)] = src
__global__ void k_fill(const int* __restrict__ ei, int E, const int* __restrict__ flags,
                       int* __restrict__ cursor, int* __restrict__ csr) {
    int i = blockIdx.x * blockDim.x + threadIdx.x;
    if (i >= E) return;
    int s, d;
    if (flags[1]) { s = ei[2 * i];     d = ei[2 * E + 2 * i]; }
    else          { s = ei[i];         d = ei[E + i]; }
    int p = atomicAdd(&cursor[d], 1);
    csr[p] = s;
}

// C[M,256] = A[M,256] @ Bt^T. 1D grid; wave computes 16 rows x 256 cols.
__global__ __launch_bounds__(256) void k_gemm(const unsigned short* __restrict__ A,
                                              const unsigned short* __restrict__ Bt,
                                              unsigned short* __restrict__ C, int M) {
    int tid  = threadIdx.x;
    int lane = tid & 63;
    int wave = tid >> 6;
    int q = lane >> 4;
    int r = lane & 15;
    int rowBase = blockIdx.x * 64 + wave * 16;

    int arow = rowBase + r;
    arow = arow < M ? arow : M - 1;
    const unsigned short* aptr = A + (size_t)arow * 256;

    f32x4 acc[16] = {};
    for (int kk = 0; kk < 256; kk += 32) {
        int k = kk + q * 8;
        bf16x8 a = *(const bf16x8*)(aptr + k);
#pragma unroll
        for (int nt = 0; nt < 16; ++nt) {
            bf16x8 b = *(const bf16x8*)(Bt + (size_t)(nt * 16 + r) * 256 + k);
            acc[nt] = __builtin_amdgcn_mfma_f32_16x16x32_bf16(a, b, acc[nt], 0, 0, 0);
        }
    }
#pragma unroll
    for (int nt = 0; nt < 16; ++nt) {
        int col = nt * 16 + r;
#pragma unroll
        for (int r2 = 0; r2 < 4; ++r2) {
            int row = rowBase + q * 4 + r2;
            if (row < M) C[(size_t)row * 256 + col] = f2bf(acc[nt][r2]);
        }
    }
}

// XCD-pinned channel-chunked aggregation.
// Flat grid: blk = grp*8 + chunk; chunk = blk%8 rides round-robin XCD dispatch, so
// XCD c only touches channel slice [32c,32c+32) -> 3.2 MB, L2-resident, fetched once.
// Wave = 1 node: 8 edge-slots x 8 lanes x 4 channels (8B gathers, 64 B/row).
__global__ __launch_bounds__(256) void k_agg(const unsigned short* __restrict__ XW,
                                             const int* __restrict__ csr,
                                             const int* __restrict__ offs,
                                             const float* __restrict__ dinv,
                                             const void* __restrict__ bias,
                                             void* __restrict__ out,
                                             int relu, int final_, const int* __restrict__ flags,
                                             int N) {
    int blk   = blockIdx.x;
    int chunk = blk & 7;
    int grp   = blk >> 3;
    int v = grp * 4 + (threadIdx.x >> 6);
    if (v >= N) return;
    int lane = threadIdx.x & 63;
    int slot = lane >> 3;              // 0..7
    int r8   = lane & 7;               // 0..7
    int c = chunk * 32 + r8 * 4;       // 4 channels per lane
    float a0 = 0.f, a1 = 0.f, a2 = 0.f, a3 = 0.f;
    int beg = offs[v], end = offs[v + 1];
    for (int e0 = beg; e0 < end; e0 += 8) {
        int e = e0 + slot;
        if (e < end) {
            int s = csr[e];
            float w = dinv[s];
            uint2 u = *(const uint2*)(XW + (size_t)s * 256 + c);
            a0 += w * bf2f((unsigned short)(u.x & 0xffffu));
            a1 += w * bf2f((unsigned short)(u.x >> 16));
            a2 += w * bf2f((unsigned short)(u.y & 0xffffu));
            a3 += w * bf2f((unsigned short)(u.y >> 16));
        }
    }
    // reduce across the 8 slots (lane bits 3..5)
    a0 += __shfl_xor(a0, 8);  a1 += __shfl_xor(a1, 8);
    a2 += __shfl_xor(a2, 8);  a3 += __shfl_xor(a3, 8);
    a0 += __shfl_xor(a0, 16); a1 += __shfl_xor(a1, 16);
    a2 += __shfl_xor(a2, 16); a3 += __shfl_xor(a3, 16);
    a0 += __shfl_xor(a0, 32); a1 += __shfl_xor(a1, 32);
    a2 += __shfl_xor(a2, 32); a3 += __shfl_xor(a3, 32);
    if (slot == 0) {
        float dv = dinv[v];
        float dv2 = dv * dv;
        uint2 su = *(const uint2*)(XW + (size_t)v * 256 + c);
        float b0, b1, b2, b3;
        if (flags[0]) {
            const float* bf = (const float*)bias;
            b0 = bf[c]; b1 = bf[c + 1]; b2 = bf[c + 2]; b3 = bf[c + 3];
        } else {
            const unsigned short* bb = (const unsigned short*)bias;
            b0 = bf2f(bb[c]); b1 = bf2f(bb[c + 1]); b2 = bf2f(bb[c + 2]); b3 = bf2f(bb[c + 3]);
        }
        float r0 = dv * a0 + dv2 * bf2f((unsigned short)(su.x & 0xffffu)) + b0;
        float r1 = dv * a1 + dv2 * bf2f((unsigned short)(su.x >> 16))     + b1;
        float r2 = dv * a2 + dv2 * bf2f((unsigned short)(su.y & 0xffffu)) + b2;
        float r3 = dv * a3 + dv2 * bf2f((unsigned short)(su.y >> 16))     + b3;
        if (relu) {
            r0 = fmaxf(r0, 0.f); r1 = fmaxf(r1, 0.f);
            r2 = fmaxf(r2, 0.f); r3 = fmaxf(r3, 0.f);
        }
        if (final_ && flags[0]) {
            float4 o; o.x = r0; o.y = r1; o.z = r2; o.w = r3;
            *(float4*)((float*)out + (size_t)v * 256 + c) = o;
        } else {
            uint2 o;
            o.x = (unsigned)f2bf(r0) | ((unsigned)f2bf(r1) << 16);
            o.y = (unsigned)f2bf(r2) | ((unsigned)f2bf(r3) << 16);
            *(uint2*)((unsigned short*)out + (size_t)v * 256 + c) = o;
        }
    }
}

extern "C" void kernel_launch(void* const* d_in, const int* in_sizes, int n_in,
                              void* d_out, int out_size, void* d_ws, size_t ws_size,
                              hipStream_t stream) {
    (void)n_in; (void)out_size; (void)ws_size;
    const void* x  = d_in[0];
    const int*  ei = (const int*)d_in[1];
    const void* W1 = d_in[2];
    const void* b1 = d_in[3];
    const void* W2 = d_in[4];
    const void* b2 = d_in[5];

    int N = in_sizes[0] / 256;          // 50000
    int E = in_sizes[1] / 2;            // 1600000

    char* p = (char*)d_ws;
    auto alloc = [&](size_t bytes) {
        char* r = p;
        p += (bytes + 255) & ~(size_t)255;
        return r;
    };
    int*            flags  = (int*)alloc(8);
    int*            deg    = (int*)alloc((size_t)N * 4);
    int*            cursor = (int*)alloc((size_t)N * 4);
    int*            offs   = (int*)alloc(((size_t)N + 1) * 4);
    float*          dinv   = (float*)alloc((size_t)N * 4);
    int*            bsum   = (int*)alloc(1024 * 4);
    int*            bpref  = (int*)alloc(1024 * 4);
    unsigned short* wt1    = (unsigned short*)alloc(256 * 256 * 2);
    unsigned short* wt2    = (unsigned short*)alloc(256 * 256 * 2);
    int*            csr    = (int*)alloc((size_t)E * 4);
    unsigned short* buf0   = (unsigned short*)alloc((size_t)N * 256 * 2);
    unsigned short* buf1   = (unsigned short*)alloc((size_t)N * 256 * 2);

    int nF = N * 256;
    int gE = (E + 255) / 256;
    int nb = (N + 255) / 256;           // 196

    k_flags<<<1, 64, 0, stream>>>((const unsigned*)x, ei, E, flags);
    k_zero<<<nb, 256, 0, stream>>>(deg, N);
    k_count<<<gE, 256, 0, stream>>>(ei, E, flags, deg);
    k_bsum<<<nb, 256, 0, stream>>>(deg, bsum, N);
    k_bscan<<<1, 1024, 0, stream>>>(bsum, bpref, nb);
    k_offs<<<nb, 256, 0, stream>>>(deg, bpref, offs, cursor, dinv, N);
    k_fill<<<gE, 256, 0, stream>>>(ei, E, flags, cursor, csr);

    k_cvt8<<<(nF / 8 + 255) / 256, 256, 0, stream>>>(x, buf0, nF / 8, flags);
    k_cvtT<<<256, 256, 0, stream>>>(W1, wt1, flags);
    k_cvtT<<<256, 256, 0, stream>>>(W2, wt2, flags);

    int gAgg = ((N + 3) / 4) * 8;       // flat: grp*8 + chunk
    k_gemm<<<(N + 63) / 64, 256, 0, stream>>>(buf0, wt1, buf1, N);           // XW1
    k_agg<<<gAgg, 256, 0, stream>>>(buf1, csr, offs, dinv, b1,
                                    (void*)buf0, 1, 0, flags, N);            // h (bf16)
    k_gemm<<<(N + 63) / 64, 256, 0, stream>>>(buf0, wt2, buf1, N);           // HW2
    k_agg<<<gAgg, 256, 0, stream>>>(buf1, csr, offs, dinv, b2,
                                    d_out, 0, 1, flags, N);                  // final
}

// Round 8
// 665.963 us; speedup vs baseline: 1.9020x; 1.4337x over previous
//
#include <hip/hip_runtime.h>
#include <stdint.h>

typedef __attribute__((ext_vector_type(8))) short bf16x8;   // 8 bf16 = 4 VGPRs
typedef __attribute__((ext_vector_type(4))) float f32x4;

__device__ __forceinline__ float bf2f(unsigned short b) {
    union { unsigned u; float f; } c; c.u = ((unsigned)b) << 16; return c.f;
}
__device__ __forceinline__ unsigned short f2bf(float f) {
    union { float f; unsigned u; } c; c.f = f;
    unsigned u = c.u;
    u += 0x7fffu + ((u >> 16) & 1u);          // round-to-nearest-even
    return (unsigned short)(u >> 16);
}

__global__ void GNNEncoder_317827579954_kernel() {}

__global__ void k_zero(int* __restrict__ p, int n) {
    int i = blockIdx.x * 256 + threadIdx.x;
    if (i < n) p[i] = 0;
}

// flags[0] = 1 if dense inputs are f32 (else bf16); flags[1] = 1 if edge_index is int64.
__global__ void k_flags(const unsigned* __restrict__ x, const int* __restrict__ ei,
                        int E, int* __restrict__ flags) {
    int t = threadIdx.x;              // 0..63
    int pl = 0;
    for (int i = t; i < 256; i += 64) {
        unsigned u = x[i] & 0xffffu;
        unsigned e = (u >> 7) & 0xffu;
        if ((e >= 100u && e <= 145u) || u == 0u) ++pl;
    }
    for (int off = 32; off; off >>= 1) pl += __shfl_down(pl, off);
    int n = E < 64 ? E : 64;
    unsigned long long nz = __ballot(t < n ? (ei[2 * t + 1] != 0) : 0);
    if (t == 0) {
        flags[0] = (pl >= 192) ? 0 : 1;       // 0 = bf16, 1 = f32
        flags[1] = (nz == 0ull) ? 1 : 0;      // 1 = int64
    }
}

// Normalize x into bf16, 8 elements/thread.
__global__ void k_cvt8(const void* __restrict__ in, unsigned short* __restrict__ out,
                       int n8, const int* __restrict__ flags) {
    int i = blockIdx.x * 256 + threadIdx.x;
    if (i >= n8) return;
    if (flags[0]) {
        const float4* f = (const float4*)in;
        float4 x0 = f[i * 2], x1 = f[i * 2 + 1];
        union { unsigned short s[8]; uint4 v; } o;
        o.s[0] = f2bf(x0.x); o.s[1] = f2bf(x0.y); o.s[2] = f2bf(x0.z); o.s[3] = f2bf(x0.w);
        o.s[4] = f2bf(x1.x); o.s[5] = f2bf(x1.y); o.s[6] = f2bf(x1.z); o.s[7] = f2bf(x1.w);
        ((uint4*)out)[i] = o.v;
    } else {
        ((uint4*)out)[i] = ((const uint4*)in)[i];
    }
}

// W [k][n] (raw dtype) -> Wt [n][k] bf16 (256x256)
__global__ void k_cvtT(const void* __restrict__ W, unsigned short* __restrict__ Wt,
                       const int* __restrict__ flags) {
    int n = blockIdx.x, k = threadIdx.x;
    unsigned short v;
    if (flags[0]) v = f2bf(((const float*)W)[k * 256 + n]);
    else          v = ((const unsigned short*)W)[k * 256 + n];
    Wt[n * 256 + k] = v;
}

// deg[v] = #(dst == v)
__global__ void k_count(const int* __restrict__ ei, int E, const int* __restrict__ flags,
                        int* __restrict__ deg) {
    int i = blockIdx.x * blockDim.x + threadIdx.x;
    if (i >= E) return;
    int d = flags[1] ? ei[2 * E + 2 * i] : ei[E + i];
    atomicAdd(&deg[d], 1);
}

// ---- parallel exclusive scan over deg (3 kernels) ----
__global__ void k_bsum(const int* __restrict__ deg, int* __restrict__ bsum, int N) {
    __shared__ int sc[256];
    int t = threadIdx.x;
    int i = blockIdx.x * 256 + t;
    int d = i < N ? deg[i] : 0;
    sc[t] = d;
    __syncthreads();
    for (int off = 128; off; off >>= 1) {
        if (t < off) sc[t] += sc[t + off];
        __syncthreads();
    }
    if (t == 0) bsum[blockIdx.x] = sc[0];
}

__global__ void k_bscan(const int* __restrict__ bsum, int* __restrict__ bpref, int nb) {
    __shared__ int sc[1024];
    int t = threadIdx.x;
    if (t < nb) sc[t] = bsum[t];
    __syncthreads();
    if (t == 0) {
        int run = 0;
        for (int i = 0; i < nb; ++i) { int v = sc[i]; bpref[i] = run; run += v; }
    }
}

__global__ void k_offs(const int* __restrict__ deg, const int* __restrict__ bpref,
                       int* __restrict__ offs, int* __restrict__ cursor,
                       float* __restrict__ dinv, int N) {
    __shared__ int sc[256];
    int t = threadIdx.x;
    int i = blockIdx.x * 256 + t;
    int d = (i < N) ? deg[i] : 0;
    sc[t] = d;
    __syncthreads();
    for (int off = 1; off < 256; off <<= 1) {
        int v = (t >= off) ? sc[t - off] : 0;
        __syncthreads();
        sc[t] += v;
        __syncthreads();
    }
    if (i < N) {
        int ex = sc[t] - d + bpref[blockIdx.x];
        offs[i] = ex; cursor[i] = ex;
        dinv[i] = rsqrtf((float)(d + 1));     // +1 = self loop
        if (i == N - 1) offs[N] = ex + d;
    }
}

// counting-sort CSR fill: csr[slot(dst)] = src
__global__ void k_fill(const int* __restrict__ ei, int E, const int* __restrict__ flags,
                       int* __restrict__ cursor, int* __restrict__ csr) {
    int i = blockIdx.x * blockDim.x + threadIdx.x;
    if (i >= E) return;
    int s, d;
    if (flags[1]) { s = ei[2 * i];     d = ei[2 * E + 2 * i]; }
    else          { s = ei[i];         d = ei[E + i]; }
    int p = atomicAdd(&cursor[d], 1);
    csr[p] = s;
}

// C[M,256] = A[M,256] @ Bt^T. 1D grid; wave computes 16 rows x 256 cols.
__global__ __launch_bounds__(256) void k_gemm(const unsigned short* __restrict__ A,
                                              const unsigned short* __restrict__ Bt,
                                              unsigned short* __restrict__ C, int M) {
    int tid  = threadIdx.x;
    int lane = tid & 63;
    int wave = tid >> 6;
    int q = lane >> 4;
    int r = lane & 15;
    int rowBase = blockIdx.x * 64 + wave * 16;

    int arow = rowBase + r;
    arow = arow < M ? arow : M - 1;
    const unsigned short* aptr = A + (size_t)arow * 256;

    f32x4 acc[16] = {};
    for (int kk = 0; kk < 256; kk += 32) {
        int k = kk + q * 8;
        bf16x8 a = *(const bf16x8*)(aptr + k);
#pragma unroll
        for (int nt = 0; nt < 16; ++nt) {
            bf16x8 b = *(const bf16x8*)(Bt + (size_t)(nt * 16 + r) * 256 + k);
            acc[nt] = __builtin_amdgcn_mfma_f32_16x16x32_bf16(a, b, acc[nt], 0, 0, 0);
        }
    }
#pragma unroll
    for (int nt = 0; nt < 16; ++nt) {
        int col = nt * 16 + r;
#pragma unroll
        for (int r2 = 0; r2 < 4; ++r2) {
            int row = rowBase + q * 4 + r2;
            if (row < M) C[(size_t)row * 256 + col] = f2bf(acc[nt][r2]);
        }
    }
}

// Full-row gather aggregation with 8x edge unroll for memory-level parallelism.
// One wave per node; lane owns 4 channels (uint2 = 8 B); 64 lanes = full 512-B row.
// 8 batched gathers in flight per wave hide the ~700-900 cyc L2-miss latency.
__global__ __launch_bounds__(256) void k_agg(const unsigned short* __restrict__ XW,
                                             const int* __restrict__ csr,
                                             const int* __restrict__ offs,
                                             const float* __restrict__ dinv,
                                             const void* __restrict__ bias,
                                             void* __restrict__ out,
                                             int relu, int final_, const int* __restrict__ flags,
                                             int N) {
    int v = blockIdx.x * 4 + (threadIdx.x >> 6);
    if (v >= N) return;
    int lane = threadIdx.x & 63;
    int c = lane * 4;
    float a0 = 0.f, a1 = 0.f, a2 = 0.f, a3 = 0.f;
    int beg = offs[v], end = offs[v + 1];
    int e = beg;
    for (; e + 8 <= end; e += 8) {
        int s[8]; float w[8]; uint2 u[8];
#pragma unroll
        for (int j = 0; j < 8; ++j) s[j] = csr[e + j];
#pragma unroll
        for (int j = 0; j < 8; ++j) w[j] = dinv[s[j]];
#pragma unroll
        for (int j = 0; j < 8; ++j) u[j] = *(const uint2*)(XW + (size_t)s[j] * 256 + c);
#pragma unroll
        for (int j = 0; j < 8; ++j) {
            a0 += w[j] * bf2f((unsigned short)(u[j].x & 0xffffu));
            a1 += w[j] * bf2f((unsigned short)(u[j].x >> 16));
            a2 += w[j] * bf2f((unsigned short)(u[j].y & 0xffffu));
            a3 += w[j] * bf2f((unsigned short)(u[j].y >> 16));
        }
    }
    for (; e < end; ++e) {
        int s = csr[e];
        float w = dinv[s];
        uint2 u = *(const uint2*)(XW + (size_t)s * 256 + c);
        a0 += w * bf2f((unsigned short)(u.x & 0xffffu));
        a1 += w * bf2f((unsigned short)(u.x >> 16));
        a2 += w * bf2f((unsigned short)(u.y & 0xffffu));
        a3 += w * bf2f((unsigned short)(u.y >> 16));
    }
    float dv = dinv[v];
    float dv2 = dv * dv;
    uint2 su = *(const uint2*)(XW + (size_t)v * 256 + c);
    float b0, b1, b2, b3;
    if (flags[0]) {
        const float* bf = (const float*)bias;
        b0 = bf[c]; b1 = bf[c + 1]; b2 = bf[c + 2]; b3 = bf[c + 3];
    } else {
        const unsigned short* bb = (const unsigned short*)bias;
        b0 = bf2f(bb[c]); b1 = bf2f(bb[c + 1]); b2 = bf2f(bb[c + 2]); b3 = bf2f(bb[c + 3]);
    }
    float r0 = dv * a0 + dv2 * bf2f((unsigned short)(su.x & 0xffffu)) + b0;
    float r1 = dv * a1 + dv2 * bf2f((unsigned short)(su.x >> 16))     + b1;
    float r2 = dv * a2 + dv2 * bf2f((unsigned short)(su.y & 0xffffu)) + b2;
    float r3 = dv * a3 + dv2 * bf2f((unsigned short)(su.y >> 16))     + b3;
    if (relu) {
        r0 = fmaxf(r0, 0.f); r1 = fmaxf(r1, 0.f);
        r2 = fmaxf(r2, 0.f); r3 = fmaxf(r3, 0.f);
    }
    if (final_ && flags[0]) {
        float4 o; o.x = r0; o.y = r1; o.z = r2; o.w = r3;
        *(float4*)((float*)out + (size_t)v * 256 + c) = o;
    } else {
        uint2 o;
        o.x = (unsigned)f2bf(r0) | ((unsigned)f2bf(r1) << 16);
        o.y = (unsigned)f2bf(r2) | ((unsigned)f2bf(r3) << 16);
        *(uint2*)((unsigned short*)out + (size_t)v * 256 + c) = o;
    }
}

extern "C" void kernel_launch(void* const* d_in, const int* in_sizes, int n_in,
                              void* d_out, int out_size, void* d_ws, size_t ws_size,
                              hipStream_t stream) {
    (void)n_in; (void)out_size; (void)ws_size;
    const void* x  = d_in[0];
    const int*  ei = (const int*)d_in[1];
    const void* W1 = d_in[2];
    const void* b1 = d_in[3];
    const void* W2 = d_in[4];
    const void* b2 = d_in[5];

    int N = in_sizes[0] / 256;          // 50000
    int E = in_sizes[1] / 2;            // 1600000

    char* p = (char*)d_ws;
    auto alloc = [&](size_t bytes) {
        char* r = p;
        p += (bytes + 255) & ~(size_t)255;
        return r;
    };
    int*            flags  = (int*)alloc(8);
    int*            deg    = (int*)alloc((size_t)N * 4);
    int*            cursor = (int*)alloc((size_t)N * 4);
    int*            offs   = (int*)alloc(((size_t)N + 1) * 4);
    float*          dinv   = (float*)alloc((size_t)N * 4);
    int*            bsum   = (int*)alloc(1024 * 4);
    int*            bpref  = (int*)alloc(1024 * 4);
    unsigned short* wt1    = (unsigned short*)alloc(256 * 256 * 2);
    unsigned short* wt2    = (unsigned short*)alloc(256 * 256 * 2);
    int*            csr    = (int*)alloc((size_t)E * 4);
    unsigned short* buf0   = (unsigned short*)alloc((size_t)N * 256 * 2);
    unsigned short* buf1   = (unsigned short*)alloc((size_t)N * 256 * 2);

    int nF = N * 256;
    int gE = (E + 255) / 256;
    int nb = (N + 255) / 256;           // 196

    k_flags<<<1, 64, 0, stream>>>((const unsigned*)x, ei, E, flags);
    k_zero<<<nb, 256, 0, stream>>>(deg, N);
    k_count<<<gE, 256, 0, stream>>>(ei, E, flags, deg);
    k_bsum<<<nb, 256, 0, stream>>>(deg, bsum, N);
    k_bscan<<<1, 1024, 0, stream>>>(bsum, bpref, nb);
    k_offs<<<nb, 256, 0, stream>>>(deg, bpref, offs, cursor, dinv, N);
    k_fill<<<gE, 256, 0, stream>>>(ei, E, flags, cursor, csr);

    k_cvt8<<<(nF / 8 + 255) / 256, 256, 0, stream>>>(x, buf0, nF / 8, flags);
    k_cvtT<<<256, 256, 0, stream>>>(W1, wt1, flags);
    k_cvtT<<<256, 256, 0, stream>>>(W2, wt2, flags);

    int gAgg = (N + 3) / 4;
    k_gemm<<<(N + 63) / 64, 256, 0, stream>>>(buf0, wt1, buf1, N);           // XW1
    k_agg<<<gAgg, 256, 0, stream>>>(buf1, csr, offs, dinv, b1,
                                    (void*)buf0, 1, 0, flags, N);            // h (bf16)
    k_gemm<<<(N + 63) / 64, 256, 0, stream>>>(buf0, wt2, buf1, N);           // HW2
    k_agg<<<gAgg, 256, 0, stream>>>(buf1, csr, offs, dinv, b2,
                                    d_out, 0, 1, flags, N);                  // final
}